// Round 11
// baseline (2766.967 us; speedup 1.0000x reference)
//
#include <hip/hip_runtime.h>
#include <math.h>

// dims (hardcoded per reference)
#define T_STEPS 50
#define BB 8   // batch rows per block; grid = 2048/8 = 256 blocks = 1 per CU

// ws float offsets — k-pair-interleaved weight layouts ([k/2][col][2] per stream)
#define OFF_WK2   0        // [32][64][2]        = 4096
#define OFF_WQ2   4096     // [6][32][64][2]     = 24576
#define OFF_WC2   28672    // [6][32][192][2]    = 73728  (Wv@W_ih fused, paired)
#define OFF_WH2   102400   // [6][32][192][2]    = 73728
#define OFF_WQC2  176128   // [6][32][128][2]    = 49152
#define OFF_WKC2  225280   // [6][32][128][2]    = 49152
#define OFF_WVC2  274432   // [6][32][64][2]     = 24576
#define WS_TOTAL  299008   // floats = 1.196 MB

// LDS pool offsets (floats)
#define O_XH    0        // xh_T[64][8]  k-major (uniform b128 broadcast reads)
#define O_HT    512      // h_T[6][64][8]
#define O_HNT   3584     // hn_T[6][64][8]
#define O_K0    6656     // K0[8][64] row-major
#define O_Q     7168     // Q[6][8][64]
#define O_QC    10240    // qc[6][8][128]
#define O_KC    16384    // kc[6][8][128]
#define O_VC    22528    // vc[6][8][64]
#define O_P0    25600    // p0[8][6]
#define O_ACT   25648    // act[8][6]
#define POOL_F  25696    // 102,784 B LDS

__device__ __forceinline__ void fma4(float4& a, const float4 v, const float s) {
  a.x = fmaf(v.x, s, a.x); a.y = fmaf(v.y, s, a.y);
  a.z = fmaf(v.z, s, a.z); a.w = fmaf(v.w, s, a.w);
}
__device__ __forceinline__ float sigmoidf_(float x) { return 1.0f / (1.0f + __expf(-x)); }
__device__ __forceinline__ float tanhf_(float x) {
  float ax = fabsf(x);
  float e = __expf(-2.0f * ax);
  float t = (1.0f - e) / (1.0f + e);
  return copysignf(t, x);
}

// Wcomb[r][f][g] = sum_v Wv[f][v]*Wih[r][v][g], written k-pair-interleaved
__global__ void wcombP_kernel(const float* __restrict__ Wv, const float* __restrict__ Wih,
                              float* __restrict__ ws) {
  int g = threadIdx.x;          // 0..191
  int f = blockIdx.x & 63;      // 0..63 (k index)
  int r = blockIdx.x >> 6;      // 0..5
  float acc = 0.f;
#pragma unroll 8
  for (int v = 0; v < 128; ++v)
    acc = fmaf(Wv[f * 128 + v], Wih[(r * 128 + v) * 192 + g], acc);
  ws[OFF_WC2 + r * 12288 + (f >> 1) * 384 + g * 2 + (f & 1)] = acc;
}

// pack remaining weight streams into k-pair-interleaved layouts.
// index space: WK2 4096 | WQ2 24576 | WH2 73728 | WQC2 49152 | WKC2 49152 | WVC2 24576
// total 225280 = 880 blocks x 256
__global__ void packP_kernel(const float* __restrict__ Wk, const float* __restrict__ Wq,
                             const float* __restrict__ Whh, const float* __restrict__ Wqc,
                             const float* __restrict__ Wkc, const float* __restrict__ Wvc,
                             float* __restrict__ ws) {
  int i = blockIdx.x * 256 + threadIdx.x;
  if (i < 4096) {                       // WK2: [64][64]
    int k = i >> 6, c = i & 63;
    ws[OFF_WK2 + (k >> 1) * 128 + c * 2 + (k & 1)] = Wk[k * 64 + c];
  } else if (i < 28672) {               // WQ2: 6 x [64][64]
    int j = i - 4096; int r = j >> 12, rem = j & 4095, k = rem >> 6, c = rem & 63;
    ws[OFF_WQ2 + r * 4096 + (k >> 1) * 128 + c * 2 + (k & 1)] = Wq[r * 4096 + k * 64 + c];
  } else if (i < 102400) {              // WH2: 6 x [64][192]
    int j = i - 28672; int r = j / 12288, rem = j % 12288, k = rem / 192, g = rem % 192;
    ws[OFF_WH2 + r * 12288 + (k >> 1) * 384 + g * 2 + (k & 1)] = Whh[r * 12288 + k * 192 + g];
  } else if (i < 151552) {              // WQC2: 6 x [64][128]
    int j = i - 102400; int r = j >> 13, rem = j & 8191, k = rem >> 7, g = rem & 127;
    ws[OFF_WQC2 + r * 8192 + (k >> 1) * 256 + g * 2 + (k & 1)] = Wqc[r * 8192 + k * 128 + g];
  } else if (i < 200704) {              // WKC2: 6 x [64][128]
    int j = i - 151552; int r = j >> 13, rem = j & 8191, k = rem >> 7, g = rem & 127;
    ws[OFF_WKC2 + r * 8192 + (k >> 1) * 256 + g * 2 + (k & 1)] = Wkc[r * 8192 + k * 128 + g];
  } else if (i < 225280) {              // WVC2: 6 x [64][64]
    int j = i - 200704; int r = j >> 12, rem = j & 4095, k = rem >> 6, g = rem & 63;
    ws[OFF_WVC2 + r * 4096 + (k >> 1) * 128 + g * 2 + (k & 1)] = Wvc[r * 4096 + k * 64 + g];
  }
}

// waves_per_eu(4,4): 128-VGPR cap for the 16-wave block (R6: default -> 64 -> squeeze).
__global__ __launch_bounds__(1024, 1) __attribute__((amdgpu_waves_per_eu(4, 4)))
void rims_kernel(
    const float* __restrict__ x, const float* __restrict__ statics,
    const float* __restrict__ maskp, const float* __restrict__ delta,
    const float* __restrict__ xlast, const float* __restrict__ xmean,
    const float* __restrict__ wdgp, const float* __restrict__ bdgp,
    const float* __restrict__ bih, const float* __restrict__ bhh,
    const float* __restrict__ W1, const float* __restrict__ b1,
    const float* __restrict__ W2, const float* __restrict__ b2,
    const float* __restrict__ ws, float* __restrict__ out) {
  __shared__ float pool[POOL_F];

  const int tid = threadIdx.x;
  const int wave = tid >> 6;   // 0..15
  const int lane = tid & 63;
  const int b0 = blockIdx.x * BB;

  for (int i = tid; i < 3072; i += 1024) pool[O_HT + i] = 0.f;

  const float wdg = wdgp[lane];
  const float bdg = bdgp[lane];
  const float xmv = xmean[(size_t)(b0 + (wave & 7)) * 64 + lane];
  // G1 biases (waves 0..11 own rim r = wave>>1); r/z biases pre-combined (R8-proven)
  float bR = 0.f, bZ = 0.f, bin = 0.f, bhn = 0.f;
  if (wave < 12) {
    const int r = wave >> 1;
    bR = bih[r * 192 + lane] + bhh[r * 192 + lane];
    bZ = bih[r * 192 + 64 + lane] + bhh[r * 192 + 64 + lane];
    bin = bih[r * 192 + 128 + lane];
    bhn = bhh[r * 192 + 128 + lane];
  }
  // X for t=0 (waves 0..7, row = wave)
  if (wave < 8) {
    size_t off = ((size_t)(b0 + wave) * T_STEPS + 0) * 64 + lane;
    float xt = x[off], mt = maskp[off], dt = delta[off], xl = xlast[off];
    float gm = __expf(-fmaxf(fmaf(dt, wdg, bdg), 0.f));
    pool[O_XH + lane * 8 + wave] = mt * xt + (1.f - mt) * (gm * xl + (1.f - gm) * xmv);
  }
  __syncthreads();

  for (int t = 0; t < T_STEPS; ++t) {
    // ===== G0: 14 units = (proj p 0..6) x (row-quad q); pair-loads + prefetch
    if (wave < 14) {
      const int p = wave >> 1, q = wave & 1;
      const float2* Wp = (p == 0) ? (const float2*)(ws + OFF_WK2)
                                  : ((const float2*)(ws + OFF_WQ2) + (p - 1) * 2048);
      const float* src = (p == 0) ? (pool + O_XH) : (pool + O_HT + (p - 1) * 512);
      float4 acc = {0, 0, 0, 0};
      float2 w = Wp[lane];
#pragma unroll 4
      for (int k2 = 0; k2 < 32; ++k2) {
        float2 nw = Wp[((k2 + 1) & 31) * 64 + lane];
        const float* s = src + k2 * 16 + q * 4;
        float4 a0 = *(const float4*)&s[0];   // k = 2k2, rows q*4..q*4+3
        float4 a1 = *(const float4*)&s[8];   // k = 2k2+1
        fma4(acc, a0, w.x); fma4(acc, a1, w.y);
        w = nw;
      }
      float* dst = (p == 0) ? (pool + O_K0) : (pool + O_Q + (p - 1) * 512);
      dst[(q * 4 + 0) * 64 + lane] = acc.x; dst[(q * 4 + 1) * 64 + lane] = acc.y;
      dst[(q * 4 + 2) * 64 + lane] = acc.z; dst[(q * 4 + 3) * 64 + lane] = acc.w;
    }
    __syncthreads();
    // ===== R: logits, p0, top-4 mask (waves 0..7, row = wave)
    if (wave < 8) {
      const int row = wave;
      float k0 = pool[O_K0 + row * 64 + lane];
      float logit[6];
#pragma unroll
      for (int r = 0; r < 6; ++r) {
        float p = pool[O_Q + (r * 8 + row) * 64 + lane] * k0;
#pragma unroll
        for (int d = 1; d < 64; d <<= 1) p += __shfl_xor(p, d, 64);
        logit[r] = p * 0.125f;  // 1/sqrt(KS)
      }
      if (lane == 0) {
#pragma unroll
        for (int r = 0; r < 6; ++r) {
          int rank = 0;
#pragma unroll
          for (int r2 = 0; r2 < 6; ++r2)
            rank += (logit[r2] > logit[r]) || (logit[r2] == logit[r] && r2 < r);
          pool[O_P0 + row * 6 + r] = sigmoidf_(logit[r]);   // softmax([l,0])[0]
          pool[O_ACT + row * 6 + r] = (rank < 4) ? 1.f : 0.f;
        }
      }
    }
    __syncthreads();
    // ===== G1: 12 units = (rim r, row-quad q); pair-loads + prefetch; GRU inline
    if (wave < 12) {
      const int r = wave >> 1, q = wave & 1;
      const float2* Wc2 = (const float2*)(ws + OFF_WC2) + r * 6144;
      const float2* Wh2 = (const float2*)(ws + OFF_WH2) + r * 6144;
      float4 ur = {0,0,0,0}, uz = {0,0,0,0}, un = {0,0,0,0};
      float4 gr = {0,0,0,0}, gz = {0,0,0,0}, gn = {0,0,0,0};
      float2 w0 = Wc2[lane], w1 = Wc2[64 + lane], w2 = Wc2[128 + lane];
      float2 v0 = Wh2[lane], v1 = Wh2[64 + lane], v2 = Wh2[128 + lane];
#pragma unroll 4
      for (int k2 = 0; k2 < 32; ++k2) {
        const int kn = ((k2 + 1) & 31) * 192;
        float2 nw0 = Wc2[kn + lane], nw1 = Wc2[kn + 64 + lane], nw2 = Wc2[kn + 128 + lane];
        float2 nv0 = Wh2[kn + lane], nv1 = Wh2[kn + 64 + lane], nv2 = Wh2[kn + 128 + lane];
        const float* xs = pool + O_XH + k2 * 16 + q * 4;
        const float* hs = pool + O_HT + r * 512 + k2 * 16 + q * 4;
        float4 xa = *(const float4*)&xs[0], xb = *(const float4*)&xs[8];
        float4 ha = *(const float4*)&hs[0], hb = *(const float4*)&hs[8];
        fma4(ur, xa, w0.x); fma4(ur, xb, w0.y);
        fma4(uz, xa, w1.x); fma4(uz, xb, w1.y);
        fma4(un, xa, w2.x); fma4(un, xb, w2.y);
        fma4(gr, ha, v0.x); fma4(gr, hb, v0.y);
        fma4(gz, ha, v1.x); fma4(gz, hb, v1.y);
        fma4(gn, ha, v2.x); fma4(gn, hb, v2.y);
        w0 = nw0; w1 = nw1; w2 = nw2; v0 = nv0; v1 = nv1; v2 = nv2;
      }
      float4 hold = *(const float4*)&pool[O_HT + (r * 64 + lane) * 8 + q * 4];
      auto gru1 = [&](float p0v, float u0, float u1, float u2, float g0, float g1,
                      float g2, float holdv) -> float {
        float rg = sigmoidf_(fmaf(p0v, u0, g0) + bR);
        float zg = sigmoidf_(fmaf(p0v, u1, g1) + bZ);
        float ng = tanhf_(fmaf(p0v, u2, bin) + rg * (g2 + bhn));
        return (1.f - zg) * ng + zg * holdv;
      };
      float4 hn;
      hn.x = gru1(pool[O_P0 + (q * 4 + 0) * 6 + r], ur.x, uz.x, un.x, gr.x, gz.x, gn.x, hold.x);
      hn.y = gru1(pool[O_P0 + (q * 4 + 1) * 6 + r], ur.y, uz.y, un.y, gr.y, gz.y, gn.y, hold.y);
      hn.z = gru1(pool[O_P0 + (q * 4 + 2) * 6 + r], ur.z, uz.z, un.z, gr.z, gz.z, gn.z, hold.z);
      hn.w = gru1(pool[O_P0 + (q * 4 + 3) * 6 + r], ur.w, uz.w, un.w, gr.w, gz.w, gn.w, hold.w);
      *(float4*)&pool[O_HNT + (r * 64 + lane) * 8 + q * 4] = hn;
    }
    __syncthreads();
    // ===== C1: 36 units = {qc,kc}x(rim,quad) 24 + vc x(rim,quad) 12; pair+prefetch
    for (int u = wave; u < 36; u += 16) {
      if (u < 24) {
        const int v = (u < 12) ? u : (u - 12);
        const int r = v >> 1, q = v & 1;
        const float2* Wp = (const float2*)(ws + ((u < 12) ? OFF_WQC2 : OFF_WKC2)) + r * 4096;
        const float* hs0 = pool + O_HNT + r * 512 + q * 4;
        float4 a0 = {0,0,0,0}, a1 = {0,0,0,0};
        float2 wa = Wp[lane], wb = Wp[64 + lane];
#pragma unroll 4
        for (int k2 = 0; k2 < 32; ++k2) {
          const int kn = ((k2 + 1) & 31) * 128;
          float2 na = Wp[kn + lane], nb = Wp[kn + 64 + lane];
          const float* hs = hs0 + k2 * 16;
          float4 ha = *(const float4*)&hs[0], hb = *(const float4*)&hs[8];
          fma4(a0, ha, wa.x); fma4(a0, hb, wa.y);
          fma4(a1, ha, wb.x); fma4(a1, hb, wb.y);
          wa = na; wb = nb;
        }
        float* dst = pool + ((u < 12) ? O_QC : O_KC) + r * 1024;
        dst[(q * 4 + 0) * 128 + lane] = a0.x; dst[(q * 4 + 1) * 128 + lane] = a0.y;
        dst[(q * 4 + 2) * 128 + lane] = a0.z; dst[(q * 4 + 3) * 128 + lane] = a0.w;
        dst[(q * 4 + 0) * 128 + 64 + lane] = a1.x; dst[(q * 4 + 1) * 128 + 64 + lane] = a1.y;
        dst[(q * 4 + 2) * 128 + 64 + lane] = a1.z; dst[(q * 4 + 3) * 128 + 64 + lane] = a1.w;
      } else {
        const int v = u - 24;
        const int r = v >> 1, q = v & 1;
        const float2* Wp = (const float2*)(ws + OFF_WVC2) + r * 2048;
        const float* hs0 = pool + O_HNT + r * 512 + q * 4;
        float4 a0 = {0,0,0,0};
        float2 wa = Wp[lane];
#pragma unroll 4
        for (int k2 = 0; k2 < 32; ++k2) {
          const int kn = ((k2 + 1) & 31) * 64;
          float2 na = Wp[kn + lane];
          const float* hs = hs0 + k2 * 16;
          float4 ha = *(const float4*)&hs[0], hb = *(const float4*)&hs[8];
          fma4(a0, ha, wa.x); fma4(a0, hb, wa.y);
          wa = na;
        }
        float* dst = pool + O_VC + r * 512;
        dst[(q * 4 + 0) * 64 + lane] = a0.x; dst[(q * 4 + 1) * 64 + lane] = a0.y;
        dst[(q * 4 + 2) * 64 + lane] = a0.z; dst[(q * 4 + 3) * 64 + lane] = a0.w;
      }
    }
    __syncthreads();
    // ===== C2 + X(t+1): 16 units = (row, rim-half); act from ACT
    {
      float nx = 0.f, nm = 0.f, nd = 0.f, nxl = 0.f;
      if (wave < 8) {   // issue next-step input loads early; latency hides under C2
        const int tn = (t + 1 < T_STEPS) ? (t + 1) : (T_STEPS - 1);
        size_t off = ((size_t)(b0 + wave) * T_STEPS + tn) * 64 + lane;
        nx = x[off]; nm = maskp[off]; nd = delta[off]; nxl = xlast[off];
      }
      const int row = wave >> 1;
      const int half = wave & 1;
      float kcA[6], kcB[6], vcv[6];
#pragma unroll
      for (int s = 0; s < 6; ++s) {
        kcA[s] = pool[O_KC + s * 1024 + row * 128 + lane];
        kcB[s] = pool[O_KC + s * 1024 + row * 128 + 64 + lane];
        vcv[s] = pool[O_VC + s * 512 + row * 64 + lane];
      }
      const int cOut = lane >> 4;
      const int srcLane = (cOut & 1) << 5;
      const float inv_sq = 0.17677669529663687f;  // 1/sqrt(QC)
#pragma unroll
      for (int jr = 0; jr < 3; ++jr) {
        const int rr = half * 3 + jr;
        float qA = pool[O_QC + rr * 1024 + row * 128 + lane];
        float qB = pool[O_QC + rr * 1024 + row * 128 + 64 + lane];
        float sL[6], sH[6];
#pragma unroll
        for (int s = 0; s < 6; ++s) {
          float p = qA * kcA[s];
          p += __shfl_xor(p, 1, 64); p += __shfl_xor(p, 2, 64); p += __shfl_xor(p, 4, 64);
          p += __shfl_xor(p, 8, 64); p += __shfl_xor(p, 16, 64);
          sL[s] = p * inv_sq;   // heads 0/1
          float q2 = qB * kcB[s];
          q2 += __shfl_xor(q2, 1, 64); q2 += __shfl_xor(q2, 2, 64);
          q2 += __shfl_xor(q2, 4, 64); q2 += __shfl_xor(q2, 8, 64);
          q2 += __shfl_xor(q2, 16, 64);
          sH[s] = q2 * inv_sq;  // heads 2/3
        }
        float mL = sL[0], mH = sH[0];
#pragma unroll
        for (int s = 1; s < 6; ++s) { mL = fmaxf(mL, sL[s]); mH = fmaxf(mH, sH[s]); }
        float sumL = 0.f, sumH = 0.f;
#pragma unroll
        for (int s = 0; s < 6; ++s) {
          sL[s] = __expf(sL[s] - mL); sumL += sL[s];
          sH[s] = __expf(sH[s] - mH); sumH += sH[s];
        }
        float rLn = 1.f / sumL, rHn = 1.f / sumH;
        float comm = 0.f;
#pragma unroll
        for (int s = 0; s < 6; ++s) {
          float tL = __shfl(sL[s] * rLn, srcLane, 64);
          float tH = __shfl(sH[s] * rHn, srcLane, 64);
          float cp = (cOut < 2) ? tL : tH;
          comm = fmaf(cp, vcv[s], comm);
        }
        float mk = pool[O_ACT + row * 6 + rr];
        float hnv = pool[O_HNT + (rr * 64 + lane) * 8 + row];
        float hov = pool[O_HT + (rr * 64 + lane) * 8 + row];
        pool[O_HT + (rr * 64 + lane) * 8 + row] = (mk > 0.5f) ? (hnv + comm) : hov;
      }
      if (wave < 8) {
        float gm = __expf(-fmaxf(fmaf(nd, wdg, bdg), 0.f));
        pool[O_XH + lane * 8 + wave] = nm * nx + (1.f - nm) * (gm * nxl + (1.f - gm) * xmv);
      }
    }
    __syncthreads();
  }  // t

  // ---------------- final MLP head (waves 0..7, row = wave)
  if (wave < 8) {
    const int b = b0 + wave;
    float acc[10];
#pragma unroll
    for (int o = 0; o < 10; ++o) acc[o] = 0.f;
#pragma unroll
    for (int ii = 0; ii < 6; ++ii) {
      float f = pool[O_HT + (ii * 64 + lane) * 8 + wave];
      const float* w = W1 + (ii * 64 + lane) * 10;
#pragma unroll
      for (int o = 0; o < 10; ++o) acc[o] = fmaf(f, w[o], acc[o]);
    }
    if (lane < 16) {
      float f = statics[(size_t)b * 16 + lane];
      const float* w = W1 + (384 + lane) * 10;
#pragma unroll
      for (int o = 0; o < 10; ++o) acc[o] = fmaf(f, w[o], acc[o]);
    }
#pragma unroll
    for (int o = 0; o < 10; ++o) {
#pragma unroll
      for (int d = 1; d < 64; d <<= 1) acc[o] += __shfl_xor(acc[o], d, 64);
    }
    if (lane == 0) {
      float o0 = b2[0], o1 = b2[1];
#pragma unroll
      for (int o = 0; o < 10; ++o) {
        float a = fmaxf(acc[o] + b1[o], 0.f);
        o0 = fmaf(a, W2[o * 2 + 0], o0);
        o1 = fmaf(a, W2[o * 2 + 1], o1);
      }
      out[(size_t)b * 2 + 0] = o0;
      out[(size_t)b * 2 + 1] = o1;
    }
  }
}

extern "C" void kernel_launch(void* const* d_in, const int* in_sizes, int n_in,
                              void* d_out, int out_size, void* d_ws, size_t ws_size,
                              hipStream_t stream) {
  const float* x       = (const float*)d_in[0];
  const float* statics = (const float*)d_in[1];
  const float* maskp   = (const float*)d_in[2];
  const float* delta   = (const float*)d_in[3];
  const float* xlast   = (const float*)d_in[4];
  const float* xmean   = (const float*)d_in[5];
  const float* wdg     = (const float*)d_in[6];
  const float* bdg     = (const float*)d_in[7];
  const float* Wk      = (const float*)d_in[8];
  const float* Wv      = (const float*)d_in[9];
  const float* Wq      = (const float*)d_in[10];
  const float* Wih     = (const float*)d_in[11];
  const float* Whh     = (const float*)d_in[12];
  const float* bih     = (const float*)d_in[13];
  const float* bhh     = (const float*)d_in[14];
  const float* Wqc     = (const float*)d_in[15];
  const float* Wkc     = (const float*)d_in[16];
  const float* Wvc     = (const float*)d_in[17];
  const float* W1      = (const float*)d_in[18];
  const float* b1      = (const float*)d_in[19];
  const float* W2      = (const float*)d_in[20];
  const float* b2      = (const float*)d_in[21];
  float* ws = (float*)d_ws;  // needs WS_TOTAL*4 = 1,196,032 B

  wcombP_kernel<<<384, 192, 0, stream>>>(Wv, Wih, ws);
  packP_kernel<<<880, 256, 0, stream>>>(Wk, Wq, Whh, Wqc, Wkc, Wvc, ws);
  rims_kernel<<<256, 1024, 0, stream>>>(x, statics, maskp, delta, xlast, xmean,
                                        wdg, bdg, bih, bhh, W1, b1, W2, b2,
                                        ws, (float*)d_out);
}

// Round 12
// 2731.723 us; speedup vs baseline: 1.0129x; 1.0129x over previous
//
#include <hip/hip_runtime.h>
#include <math.h>

// dims (hardcoded per reference)
#define T_STEPS 50
#define BB 8   // batch rows per block; grid = 2048/8 = 256 blocks = 1 per CU

// ws float offsets — k-pair-interleaved weight layouts ([k/2][col][2] per stream)
#define OFF_WK2   0        // [32][64][2]        = 4096
#define OFF_WQ2   4096     // [6][32][64][2]     = 24576
#define OFF_WC2   28672    // [6][32][192][2]    = 73728  (Wv@W_ih fused, paired)
#define OFF_WH2   102400   // [6][32][192][2]    = 73728
#define OFF_WQC2  176128   // [6][32][128][2]    = 49152
#define OFF_WKC2  225280   // [6][32][128][2]    = 49152
#define OFF_WVC2  274432   // [6][32][64][2]     = 24576
#define WS_TOTAL  299008   // floats = 1.196 MB

// LDS pool offsets (floats)
#define O_XH    0        // xh_T[64][8]  k-major (uniform b128 broadcast reads)
#define O_HT    512      // h_T[6][64][8]
#define O_HNT   3584     // hn_T[6][64][8]
#define O_K0    6656     // K0[8][64] row-major
#define O_Q     7168     // Q[6][8][64]
#define O_QC    10240    // qc[6][8][128]
#define O_KC    16384    // kc[6][8][128]
#define O_VC    22528    // vc[6][8][64]
#define O_P0    25600    // p0[8][6]
#define O_ACT   25648    // act[8][6]
#define POOL_F  25696    // 102,784 B LDS

__device__ __forceinline__ void fma4(float4& a, const float4 v, const float s) {
  a.x = fmaf(v.x, s, a.x); a.y = fmaf(v.y, s, a.y);
  a.z = fmaf(v.z, s, a.z); a.w = fmaf(v.w, s, a.w);
}
__device__ __forceinline__ float sigmoidf_(float x) { return 1.0f / (1.0f + __expf(-x)); }
__device__ __forceinline__ float tanhf_(float x) {
  float ax = fabsf(x);
  float e = __expf(-2.0f * ax);
  float t = (1.0f - e) / (1.0f + e);
  return copysignf(t, x);
}

// Wcomb[r][f][g] = sum_v Wv[f][v]*Wih[r][v][g], written k-pair-interleaved
__global__ void wcombP_kernel(const float* __restrict__ Wv, const float* __restrict__ Wih,
                              float* __restrict__ ws) {
  int g = threadIdx.x;          // 0..191
  int f = blockIdx.x & 63;      // 0..63 (k index)
  int r = blockIdx.x >> 6;      // 0..5
  float acc = 0.f;
#pragma unroll 8
  for (int v = 0; v < 128; ++v)
    acc = fmaf(Wv[f * 128 + v], Wih[(r * 128 + v) * 192 + g], acc);
  ws[OFF_WC2 + r * 12288 + (f >> 1) * 384 + g * 2 + (f & 1)] = acc;
}

// pack remaining weight streams into k-pair-interleaved layouts.
// index space: WK2 4096 | WQ2 24576 | WH2 73728 | WQC2 49152 | WKC2 49152 | WVC2 24576
// total 225280 = 880 blocks x 256
__global__ void packP_kernel(const float* __restrict__ Wk, const float* __restrict__ Wq,
                             const float* __restrict__ Whh, const float* __restrict__ Wqc,
                             const float* __restrict__ Wkc, const float* __restrict__ Wvc,
                             float* __restrict__ ws) {
  int i = blockIdx.x * 256 + threadIdx.x;
  if (i < 4096) {                       // WK2: [64][64]
    int k = i >> 6, c = i & 63;
    ws[OFF_WK2 + (k >> 1) * 128 + c * 2 + (k & 1)] = Wk[k * 64 + c];
  } else if (i < 28672) {               // WQ2: 6 x [64][64]
    int j = i - 4096; int r = j >> 12, rem = j & 4095, k = rem >> 6, c = rem & 63;
    ws[OFF_WQ2 + r * 4096 + (k >> 1) * 128 + c * 2 + (k & 1)] = Wq[r * 4096 + k * 64 + c];
  } else if (i < 102400) {              // WH2: 6 x [64][192]
    int j = i - 28672; int r = j / 12288, rem = j % 12288, k = rem / 192, g = rem % 192;
    ws[OFF_WH2 + r * 12288 + (k >> 1) * 384 + g * 2 + (k & 1)] = Whh[r * 12288 + k * 192 + g];
  } else if (i < 151552) {              // WQC2: 6 x [64][128]
    int j = i - 102400; int r = j >> 13, rem = j & 8191, k = rem >> 7, g = rem & 127;
    ws[OFF_WQC2 + r * 8192 + (k >> 1) * 256 + g * 2 + (k & 1)] = Wqc[r * 8192 + k * 128 + g];
  } else if (i < 200704) {              // WKC2: 6 x [64][128]
    int j = i - 151552; int r = j >> 13, rem = j & 8191, k = rem >> 7, g = rem & 127;
    ws[OFF_WKC2 + r * 8192 + (k >> 1) * 256 + g * 2 + (k & 1)] = Wkc[r * 8192 + k * 128 + g];
  } else if (i < 225280) {              // WVC2: 6 x [64][64]
    int j = i - 200704; int r = j >> 12, rem = j & 4095, k = rem >> 6, g = rem & 63;
    ws[OFF_WVC2 + r * 4096 + (k >> 1) * 128 + g * 2 + (k & 1)] = Wvc[r * 4096 + k * 64 + g];
  }
}

// NO __launch_bounds__: its implied waves-per-eu shadowed our attribute and pinned
// VGPR=64 (R4..R11 evidence). flat_work_group_size(1024) + waves_per_eu(4,4)
// -> exactly 4 waves/EU -> 128-VGPR budget. LDS (103KB) already caps at 1 block/CU.
__global__ __attribute__((amdgpu_flat_work_group_size(1024, 1024), amdgpu_waves_per_eu(4, 4)))
void rims_kernel(
    const float* __restrict__ x, const float* __restrict__ statics,
    const float* __restrict__ maskp, const float* __restrict__ delta,
    const float* __restrict__ xlast, const float* __restrict__ xmean,
    const float* __restrict__ wdgp, const float* __restrict__ bdgp,
    const float* __restrict__ bih, const float* __restrict__ bhh,
    const float* __restrict__ W1, const float* __restrict__ b1,
    const float* __restrict__ W2, const float* __restrict__ b2,
    const float* __restrict__ ws, float* __restrict__ out) {
  __shared__ float pool[POOL_F];

  const int tid = threadIdx.x;
  const int wave = tid >> 6;   // 0..15
  const int lane = tid & 63;
  const int b0 = blockIdx.x * BB;

  for (int i = tid; i < 3072; i += 1024) pool[O_HT + i] = 0.f;

  const float wdg = wdgp[lane];
  const float bdg = bdgp[lane];
  const float xmv = xmean[(size_t)(b0 + (wave & 7)) * 64 + lane];
  // G1 biases (waves 0..11 own rim r = wave>>1); r/z biases pre-combined (R8-proven)
  float bR = 0.f, bZ = 0.f, bin = 0.f, bhn = 0.f;
  if (wave < 12) {
    const int r = wave >> 1;
    bR = bih[r * 192 + lane] + bhh[r * 192 + lane];
    bZ = bih[r * 192 + 64 + lane] + bhh[r * 192 + 64 + lane];
    bin = bih[r * 192 + 128 + lane];
    bhn = bhh[r * 192 + 128 + lane];
  }
  // X for t=0 (waves 0..7, row = wave)
  if (wave < 8) {
    size_t off = ((size_t)(b0 + wave) * T_STEPS + 0) * 64 + lane;
    float xt = x[off], mt = maskp[off], dt = delta[off], xl = xlast[off];
    float gm = __expf(-fmaxf(fmaf(dt, wdg, bdg), 0.f));
    pool[O_XH + lane * 8 + wave] = mt * xt + (1.f - mt) * (gm * xl + (1.f - gm) * xmv);
  }
  __syncthreads();

  for (int t = 0; t < T_STEPS; ++t) {
    // ===== G0: 14 units = (proj p 0..6) x (row-quad q); pair-loads + prefetch
    if (wave < 14) {
      const int p = wave >> 1, q = wave & 1;
      const float2* Wp = (p == 0) ? (const float2*)(ws + OFF_WK2)
                                  : ((const float2*)(ws + OFF_WQ2) + (p - 1) * 2048);
      const float* src = (p == 0) ? (pool + O_XH) : (pool + O_HT + (p - 1) * 512);
      float4 acc = {0, 0, 0, 0};
      float2 w = Wp[lane];
#pragma unroll 4
      for (int k2 = 0; k2 < 32; ++k2) {
        float2 nw = Wp[((k2 + 1) & 31) * 64 + lane];
        const float* s = src + k2 * 16 + q * 4;
        float4 a0 = *(const float4*)&s[0];   // k = 2k2, rows q*4..q*4+3
        float4 a1 = *(const float4*)&s[8];   // k = 2k2+1
        fma4(acc, a0, w.x); fma4(acc, a1, w.y);
        w = nw;
      }
      float* dst = (p == 0) ? (pool + O_K0) : (pool + O_Q + (p - 1) * 512);
      dst[(q * 4 + 0) * 64 + lane] = acc.x; dst[(q * 4 + 1) * 64 + lane] = acc.y;
      dst[(q * 4 + 2) * 64 + lane] = acc.z; dst[(q * 4 + 3) * 64 + lane] = acc.w;
    }
    __syncthreads();
    // ===== R: logits, p0, top-4 mask (waves 0..7, row = wave)
    if (wave < 8) {
      const int row = wave;
      float k0 = pool[O_K0 + row * 64 + lane];
      float logit[6];
#pragma unroll
      for (int r = 0; r < 6; ++r) {
        float p = pool[O_Q + (r * 8 + row) * 64 + lane] * k0;
#pragma unroll
        for (int d = 1; d < 64; d <<= 1) p += __shfl_xor(p, d, 64);
        logit[r] = p * 0.125f;  // 1/sqrt(KS)
      }
      if (lane == 0) {
#pragma unroll
        for (int r = 0; r < 6; ++r) {
          int rank = 0;
#pragma unroll
          for (int r2 = 0; r2 < 6; ++r2)
            rank += (logit[r2] > logit[r]) || (logit[r2] == logit[r] && r2 < r);
          pool[O_P0 + row * 6 + r] = sigmoidf_(logit[r]);   // softmax([l,0])[0]
          pool[O_ACT + row * 6 + r] = (rank < 4) ? 1.f : 0.f;
        }
      }
    }
    __syncthreads();
    // ===== G1: 12 units = (rim r, row-quad q); pair-loads + prefetch; GRU inline
    if (wave < 12) {
      const int r = wave >> 1, q = wave & 1;
      const float2* Wc2 = (const float2*)(ws + OFF_WC2) + r * 6144;
      const float2* Wh2 = (const float2*)(ws + OFF_WH2) + r * 6144;
      float4 ur = {0,0,0,0}, uz = {0,0,0,0}, un = {0,0,0,0};
      float4 gr = {0,0,0,0}, gz = {0,0,0,0}, gn = {0,0,0,0};
      float2 w0 = Wc2[lane], w1 = Wc2[64 + lane], w2 = Wc2[128 + lane];
      float2 v0 = Wh2[lane], v1 = Wh2[64 + lane], v2 = Wh2[128 + lane];
#pragma unroll 4
      for (int k2 = 0; k2 < 32; ++k2) {
        const int kn = ((k2 + 1) & 31) * 192;
        float2 nw0 = Wc2[kn + lane], nw1 = Wc2[kn + 64 + lane], nw2 = Wc2[kn + 128 + lane];
        float2 nv0 = Wh2[kn + lane], nv1 = Wh2[kn + 64 + lane], nv2 = Wh2[kn + 128 + lane];
        const float* xs = pool + O_XH + k2 * 16 + q * 4;
        const float* hs = pool + O_HT + r * 512 + k2 * 16 + q * 4;
        float4 xa = *(const float4*)&xs[0], xb = *(const float4*)&xs[8];
        float4 ha = *(const float4*)&hs[0], hb = *(const float4*)&hs[8];
        fma4(ur, xa, w0.x); fma4(ur, xb, w0.y);
        fma4(uz, xa, w1.x); fma4(uz, xb, w1.y);
        fma4(un, xa, w2.x); fma4(un, xb, w2.y);
        fma4(gr, ha, v0.x); fma4(gr, hb, v0.y);
        fma4(gz, ha, v1.x); fma4(gz, hb, v1.y);
        fma4(gn, ha, v2.x); fma4(gn, hb, v2.y);
        w0 = nw0; w1 = nw1; w2 = nw2; v0 = nv0; v1 = nv1; v2 = nv2;
      }
      float4 hold = *(const float4*)&pool[O_HT + (r * 64 + lane) * 8 + q * 4];
      auto gru1 = [&](float p0v, float u0, float u1, float u2, float g0, float g1,
                      float g2, float holdv) -> float {
        float rg = sigmoidf_(fmaf(p0v, u0, g0) + bR);
        float zg = sigmoidf_(fmaf(p0v, u1, g1) + bZ);
        float ng = tanhf_(fmaf(p0v, u2, bin) + rg * (g2 + bhn));
        return (1.f - zg) * ng + zg * holdv;
      };
      float4 hn;
      hn.x = gru1(pool[O_P0 + (q * 4 + 0) * 6 + r], ur.x, uz.x, un.x, gr.x, gz.x, gn.x, hold.x);
      hn.y = gru1(pool[O_P0 + (q * 4 + 1) * 6 + r], ur.y, uz.y, un.y, gr.y, gz.y, gn.y, hold.y);
      hn.z = gru1(pool[O_P0 + (q * 4 + 2) * 6 + r], ur.z, uz.z, un.z, gr.z, gz.z, gn.z, hold.z);
      hn.w = gru1(pool[O_P0 + (q * 4 + 3) * 6 + r], ur.w, uz.w, un.w, gr.w, gz.w, gn.w, hold.w);
      *(float4*)&pool[O_HNT + (r * 64 + lane) * 8 + q * 4] = hn;
    }
    __syncthreads();
    // ===== C1: 36 units = {qc,kc}x(rim,quad) 24 + vc x(rim,quad) 12; pair+prefetch
    for (int u = wave; u < 36; u += 16) {
      if (u < 24) {
        const int v = (u < 12) ? u : (u - 12);
        const int r = v >> 1, q = v & 1;
        const float2* Wp = (const float2*)(ws + ((u < 12) ? OFF_WQC2 : OFF_WKC2)) + r * 4096;
        const float* hs0 = pool + O_HNT + r * 512 + q * 4;
        float4 a0 = {0,0,0,0}, a1 = {0,0,0,0};
        float2 wa = Wp[lane], wb = Wp[64 + lane];
#pragma unroll 4
        for (int k2 = 0; k2 < 32; ++k2) {
          const int kn = ((k2 + 1) & 31) * 128;
          float2 na = Wp[kn + lane], nb = Wp[kn + 64 + lane];
          const float* hs = hs0 + k2 * 16;
          float4 ha = *(const float4*)&hs[0], hb = *(const float4*)&hs[8];
          fma4(a0, ha, wa.x); fma4(a0, hb, wa.y);
          fma4(a1, ha, wb.x); fma4(a1, hb, wb.y);
          wa = na; wb = nb;
        }
        float* dst = pool + ((u < 12) ? O_QC : O_KC) + r * 1024;
        dst[(q * 4 + 0) * 128 + lane] = a0.x; dst[(q * 4 + 1) * 128 + lane] = a0.y;
        dst[(q * 4 + 2) * 128 + lane] = a0.z; dst[(q * 4 + 3) * 128 + lane] = a0.w;
        dst[(q * 4 + 0) * 128 + 64 + lane] = a1.x; dst[(q * 4 + 1) * 128 + 64 + lane] = a1.y;
        dst[(q * 4 + 2) * 128 + 64 + lane] = a1.z; dst[(q * 4 + 3) * 128 + 64 + lane] = a1.w;
      } else {
        const int v = u - 24;
        const int r = v >> 1, q = v & 1;
        const float2* Wp = (const float2*)(ws + OFF_WVC2) + r * 2048;
        const float* hs0 = pool + O_HNT + r * 512 + q * 4;
        float4 a0 = {0,0,0,0};
        float2 wa = Wp[lane];
#pragma unroll 4
        for (int k2 = 0; k2 < 32; ++k2) {
          const int kn = ((k2 + 1) & 31) * 64;
          float2 na = Wp[kn + lane];
          const float* hs = hs0 + k2 * 16;
          float4 ha = *(const float4*)&hs[0], hb = *(const float4*)&hs[8];
          fma4(a0, ha, wa.x); fma4(a0, hb, wa.y);
          wa = na;
        }
        float* dst = pool + O_VC + r * 512;
        dst[(q * 4 + 0) * 64 + lane] = a0.x; dst[(q * 4 + 1) * 64 + lane] = a0.y;
        dst[(q * 4 + 2) * 64 + lane] = a0.z; dst[(q * 4 + 3) * 64 + lane] = a0.w;
      }
    }
    __syncthreads();
    // ===== C2 + X(t+1): 16 units = (row, rim-half); act from ACT
    {
      float nx = 0.f, nm = 0.f, nd = 0.f, nxl = 0.f;
      if (wave < 8) {   // issue next-step input loads early; latency hides under C2
        const int tn = (t + 1 < T_STEPS) ? (t + 1) : (T_STEPS - 1);
        size_t off = ((size_t)(b0 + wave) * T_STEPS + tn) * 64 + lane;
        nx = x[off]; nm = maskp[off]; nd = delta[off]; nxl = xlast[off];
      }
      const int row = wave >> 1;
      const int half = wave & 1;
      float kcA[6], kcB[6], vcv[6];
#pragma unroll
      for (int s = 0; s < 6; ++s) {
        kcA[s] = pool[O_KC + s * 1024 + row * 128 + lane];
        kcB[s] = pool[O_KC + s * 1024 + row * 128 + 64 + lane];
        vcv[s] = pool[O_VC + s * 512 + row * 64 + lane];
      }
      const int cOut = lane >> 4;
      const int srcLane = (cOut & 1) << 5;
      const float inv_sq = 0.17677669529663687f;  // 1/sqrt(QC)
#pragma unroll
      for (int jr = 0; jr < 3; ++jr) {
        const int rr = half * 3 + jr;
        float qA = pool[O_QC + rr * 1024 + row * 128 + lane];
        float qB = pool[O_QC + rr * 1024 + row * 128 + 64 + lane];
        float sL[6], sH[6];
#pragma unroll
        for (int s = 0; s < 6; ++s) {
          float p = qA * kcA[s];
          p += __shfl_xor(p, 1, 64); p += __shfl_xor(p, 2, 64); p += __shfl_xor(p, 4, 64);
          p += __shfl_xor(p, 8, 64); p += __shfl_xor(p, 16, 64);
          sL[s] = p * inv_sq;   // heads 0/1
          float q2 = qB * kcB[s];
          q2 += __shfl_xor(q2, 1, 64); q2 += __shfl_xor(q2, 2, 64);
          q2 += __shfl_xor(q2, 4, 64); q2 += __shfl_xor(q2, 8, 64);
          q2 += __shfl_xor(q2, 16, 64);
          sH[s] = q2 * inv_sq;  // heads 2/3
        }
        float mL = sL[0], mH = sH[0];
#pragma unroll
        for (int s = 1; s < 6; ++s) { mL = fmaxf(mL, sL[s]); mH = fmaxf(mH, sH[s]); }
        float sumL = 0.f, sumH = 0.f;
#pragma unroll
        for (int s = 0; s < 6; ++s) {
          sL[s] = __expf(sL[s] - mL); sumL += sL[s];
          sH[s] = __expf(sH[s] - mH); sumH += sH[s];
        }
        float rLn = 1.f / sumL, rHn = 1.f / sumH;
        float comm = 0.f;
#pragma unroll
        for (int s = 0; s < 6; ++s) {
          float tL = __shfl(sL[s] * rLn, srcLane, 64);
          float tH = __shfl(sH[s] * rHn, srcLane, 64);
          float cp = (cOut < 2) ? tL : tH;
          comm = fmaf(cp, vcv[s], comm);
        }
        float mk = pool[O_ACT + row * 6 + rr];
        float hnv = pool[O_HNT + (rr * 64 + lane) * 8 + row];
        float hov = pool[O_HT + (rr * 64 + lane) * 8 + row];
        pool[O_HT + (rr * 64 + lane) * 8 + row] = (mk > 0.5f) ? (hnv + comm) : hov;
      }
      if (wave < 8) {
        float gm = __expf(-fmaxf(fmaf(nd, wdg, bdg), 0.f));
        pool[O_XH + lane * 8 + wave] = nm * nx + (1.f - nm) * (gm * nxl + (1.f - gm) * xmv);
      }
    }
    __syncthreads();
  }  // t

  // ---------------- final MLP head (waves 0..7, row = wave)
  if (wave < 8) {
    const int b = b0 + wave;
    float acc[10];
#pragma unroll
    for (int o = 0; o < 10; ++o) acc[o] = 0.f;
#pragma unroll
    for (int ii = 0; ii < 6; ++ii) {
      float f = pool[O_HT + (ii * 64 + lane) * 8 + wave];
      const float* w = W1 + (ii * 64 + lane) * 10;
#pragma unroll
      for (int o = 0; o < 10; ++o) acc[o] = fmaf(f, w[o], acc[o]);
    }
    if (lane < 16) {
      float f = statics[(size_t)b * 16 + lane];
      const float* w = W1 + (384 + lane) * 10;
#pragma unroll
      for (int o = 0; o < 10; ++o) acc[o] = fmaf(f, w[o], acc[o]);
    }
#pragma unroll
    for (int o = 0; o < 10; ++o) {
#pragma unroll
      for (int d = 1; d < 64; d <<= 1) acc[o] += __shfl_xor(acc[o], d, 64);
    }
    if (lane == 0) {
      float o0 = b2[0], o1 = b2[1];
#pragma unroll
      for (int o = 0; o < 10; ++o) {
        float a = fmaxf(acc[o] + b1[o], 0.f);
        o0 = fmaf(a, W2[o * 2 + 0], o0);
        o1 = fmaf(a, W2[o * 2 + 1], o1);
      }
      out[(size_t)b * 2 + 0] = o0;
      out[(size_t)b * 2 + 1] = o1;
    }
  }
}

extern "C" void kernel_launch(void* const* d_in, const int* in_sizes, int n_in,
                              void* d_out, int out_size, void* d_ws, size_t ws_size,
                              hipStream_t stream) {
  const float* x       = (const float*)d_in[0];
  const float* statics = (const float*)d_in[1];
  const float* maskp   = (const float*)d_in[2];
  const float* delta   = (const float*)d_in[3];
  const float* xlast   = (const float*)d_in[4];
  const float* xmean   = (const float*)d_in[5];
  const float* wdg     = (const float*)d_in[6];
  const float* bdg     = (const float*)d_in[7];
  const float* Wk      = (const float*)d_in[8];
  const float* Wv      = (const float*)d_in[9];
  const float* Wq      = (const float*)d_in[10];
  const float* Wih     = (const float*)d_in[11];
  const float* Whh     = (const float*)d_in[12];
  const float* bih     = (const float*)d_in[13];
  const float* bhh     = (const float*)d_in[14];
  const float* Wqc     = (const float*)d_in[15];
  const float* Wkc     = (const float*)d_in[16];
  const float* Wvc     = (const float*)d_in[17];
  const float* W1      = (const float*)d_in[18];
  const float* b1      = (const float*)d_in[19];
  const float* W2      = (const float*)d_in[20];
  const float* b2      = (const float*)d_in[21];
  float* ws = (float*)d_ws;  // needs WS_TOTAL*4 = 1,196,032 B

  wcombP_kernel<<<384, 192, 0, stream>>>(Wv, Wih, ws);
  packP_kernel<<<880, 256, 0, stream>>>(Wk, Wq, Whh, Wqc, Wkc, Wvc, ws);
  rims_kernel<<<256, 1024, 0, stream>>>(x, statics, maskp, delta, xlast, xmean,
                                        wdg, bdg, bih, bhh, W1, b1, W2, b2,
                                        ws, (float*)d_out);
}